// Round 4
// baseline (1360.589 us; speedup 1.0000x reference)
//
#include <hip/hip_runtime.h>
#include <cstdint>
#include <cstddef>

#define ND      128
#define NNODES  50000
#define NEDGES  640000
#define BNEPS   1e-5f
#define CAP     64   // max in-degree tracked; mean=12.8, P(deg>=64) ~ 1e-18
#define BM      32   // MLP row-tile (16KB LDS -> 8+ blocks/CU)

typedef __attribute__((ext_vector_type(8))) short bf16x8;
typedef __attribute__((ext_vector_type(4))) short s16x4;
typedef __attribute__((ext_vector_type(4))) float f32x4;

__device__ __forceinline__ short f2bf(float x) {   // fp32 -> bf16 RNE
    unsigned u = __float_as_uint(x);
    unsigned r = u + 0x7fffu + ((u >> 16) & 1u);
    return (short)(r >> 16);
}
__device__ __forceinline__ float bf2f(short h) {
    return __uint_as_float(((unsigned)(unsigned short)h) << 16);
}
// XOR swizzle: spread 16B column-slots across banks per row (T2 / G4)
__device__ __forceinline__ int swz(int row, int colbyte) {
    return colbyte ^ ((row & 7) << 4);
}

// ---------- K0: split W (fp32 [k][n]) into transposed bf16 hi/lo [n][k] ----------
__global__ __launch_bounds__(128) void prep_w_kernel(
    const float* __restrict__ W1, const float* __restrict__ W2,
    short* __restrict__ w1h, short* __restrict__ w1l,
    short* __restrict__ w2h, short* __restrict__ w2l) {
    int k = blockIdx.x;            // 0..127 -> W1 row, 128..255 -> W2 row
    int n = threadIdx.x;           // 0..127 output column
    const float* W = (k < 128) ? W1 : W2;
    int kk = k & 127;
    float v = W[(size_t)kk * ND + n];
    short h = f2bf(v);
    short l = f2bf(v - bf2f(h));
    short* ph = (k < 128) ? w1h : w2h;
    short* pl = (k < 128) ? w1l : w2l;
    ph[(size_t)n * ND + kk] = h;
    pl[(size_t)n * ND + kk] = l;
}

// ---------- K1: per-edge attention logit + CSR fill (merged) ----------
__global__ __launch_bounds__(256) void attn_kernel(
    const float* __restrict__ nh, const float* __restrict__ eh,
    const int* __restrict__ ei, float* __restrict__ attn,
    int* __restrict__ deg, int* __restrict__ slots) {
    int gid = blockIdx.x * 256 + threadIdx.x;
    int e   = gid >> 5;
    int l   = threadIdx.x & 31;
    if (e >= NEDGES) return;
    int s = ei[e], d = ei[NEDGES + e];
    float4 sv = ((const float4*)(nh + (size_t)s * ND))[l];
    float4 dv = ((const float4*)(nh + (size_t)d * ND))[l];
    float4 ev = ((const float4*)(eh + (size_t)e * ND))[l];
    float acc = (sv.x + ev.x) * dv.x + (sv.y + ev.y) * dv.y +
                (sv.z + ev.z) * dv.z + (sv.w + ev.w) * dv.w;
#pragma unroll
    for (int off = 16; off > 0; off >>= 1) acc += __shfl_down(acc, off, 32);
    if (l == 0) {
        attn[e] = acc;
        int pos = atomicAdd(&deg[d], 1);
        if (pos < CAP) slots[(size_t)d * CAP + pos] = e;
    }
}

// ---------- K3: per-node softmax + weighted gather (one wave per node) ----------
__global__ __launch_bounds__(256) void gather_nz_kernel(
    const float* __restrict__ nh, const int* __restrict__ ei,
    const float* __restrict__ attn, const int* __restrict__ deg,
    const int* __restrict__ slots, float* __restrict__ nz) {
    int node = blockIdx.x * 4 + (threadIdx.x >> 6);
    int lane = threadIdx.x & 63;
    if (node >= NNODES) return;
    int dg = deg[node];
    if (dg > CAP) dg = CAP;

    int   e  = -1, si = 0;
    float a  = -3.0e38f;
    if (lane < dg) {
        e  = slots[(size_t)node * CAP + lane];
        a  = attn[e];
        si = ei[e];               // src node of this edge
    }
    float m = a;
#pragma unroll
    for (int off = 32; off > 0; off >>= 1) m = fmaxf(m, __shfl_xor(m, off, 64));
    float ex = (lane < dg) ? __expf(a - m) : 0.f;
    float sum = ex;
#pragma unroll
    for (int off = 32; off > 0; off >>= 1) sum += __shfl_xor(sum, off, 64);
    float rs = (dg > 0) ? 1.f / sum : 0.f;

    float2 acc = make_float2(0.f, 0.f);
    for (int i = 0; i < dg; ++i) {
        float al = __shfl(ex, i, 64) * rs;
        int   sv = __shfl(si, i, 64);
        float2 x = ((const float2*)(nh + (size_t)sv * ND))[lane];
        acc.x += al * x.x;
        acc.y += al * x.y;
    }
    ((float2*)(nz + (size_t)node * ND))[lane] = acc;
}

// ---------- K4: fused 2-layer MLP via split-fp32 bf16 MFMA + BN stats ----------
// MODE 0: X' = (1+eps)*nh + nz              (node, row-indexed nz)
// MODE 1: X' = (1+eps)*eh + nz[src]-nz[dst] (edge, gathered nz)
// out' = relu(X'@W1 + b1) @ W2   (b2 folded into BN shift: exact)
// BM=32 tile: LDS 16KB -> high blocks/CU for gather-latency hiding.
template <int MODE>
__global__ __launch_bounds__(256) void fused_mlp(
    const float* __restrict__ X,
    const short* __restrict__ w1h, const short* __restrict__ w1l,
    const float* __restrict__ b1,
    const short* __restrict__ w2h, const short* __restrict__ w2l,
    float* __restrict__ out, int M,
    const float* __restrict__ eps, const float* __restrict__ nz,
    const int* __restrict__ ei,
    float* __restrict__ ssum, float* __restrict__ ssq) {
    __shared__ short Ah[BM * 128];
    __shared__ short Al[BM * 128];

    int tid  = threadIdx.x;
    int lane = tid & 63;
    int wv   = tid >> 6;
    int cn   = lane & 15;   // fragment col / A row within block
    int kg   = lane >> 4;   // k-group
    int row0 = blockIdx.x * BM;
    int cbase = wv * 32;

    // ---- stage X' (BM x 128) as bf16 hi/lo into LDS (swizzled) ----
#pragma unroll
    for (int k = 0; k < BM / 8; ++k) {
        int i   = tid + k * 256;
        int r   = i >> 5;
        int c   = (i & 31) << 2;
        int row = row0 + r;
        float4 v = make_float4(0.f, 0.f, 0.f, 0.f);
        if (MODE == 1 || row < M) {
            float4 xv = *(const float4*)(X + (size_t)row * ND + c);
            float4 e4 = *(const float4*)(eps + c);
            if (MODE == 0) {
                float4 zv = *(const float4*)(nz + (size_t)row * ND + c);
                v.x = (1.f + e4.x) * xv.x + zv.x;
                v.y = (1.f + e4.y) * xv.y + zv.y;
                v.z = (1.f + e4.z) * xv.z + zv.z;
                v.w = (1.f + e4.w) * xv.w + zv.w;
            } else {
                int s = ei[row], d = ei[NEDGES + row];
                float4 zs = *(const float4*)(nz + (size_t)s * ND + c);
                float4 zd = *(const float4*)(nz + (size_t)d * ND + c);
                v.x = (1.f + e4.x) * xv.x + zs.x - zd.x;
                v.y = (1.f + e4.y) * xv.y + zs.y - zd.y;
                v.z = (1.f + e4.z) * xv.z + zs.z - zd.z;
                v.w = (1.f + e4.w) * xv.w + zs.w - zd.w;
            }
        }
        s16x4 hv, lv;
        hv.x = f2bf(v.x); lv.x = f2bf(v.x - bf2f(hv.x));
        hv.y = f2bf(v.y); lv.y = f2bf(v.y - bf2f(hv.y));
        hv.z = f2bf(v.z); lv.z = f2bf(v.z - bf2f(hv.z));
        hv.w = f2bf(v.w); lv.w = f2bf(v.w - bf2f(hv.w));
        int boff = (r << 8) + swz(r, c << 1);
        *(s16x4*)((char*)Ah + boff) = hv;
        *(s16x4*)((char*)Al + boff) = lv;
    }

    // ---- B1 fragments to registers (L2-resident; overlaps barrier wait) ----
    bf16x8 bh[2][4], bl[2][4];
#pragma unroll
    for (int cb = 0; cb < 2; ++cb) {
        int n = cbase + cb * 16 + cn;
#pragma unroll
        for (int ks = 0; ks < 4; ++ks) {
            size_t o = (size_t)n * ND + ks * 32 + kg * 8;
            bh[cb][ks] = *(const bf16x8*)(w1h + o);
            bl[cb][ks] = *(const bf16x8*)(w1l + o);
        }
    }
    float b1c[2] = { b1[cbase + cn], b1[cbase + 16 + cn] };

    f32x4 acc[2][2];
#pragma unroll
    for (int rb = 0; rb < 2; ++rb)
#pragma unroll
        for (int cb = 0; cb < 2; ++cb) acc[rb][cb] = (f32x4){0.f, 0.f, 0.f, 0.f};

    __syncthreads();   // A tile staged

    // ---- layer 1: acc += Ahi*Bhi + Ahi*Blo + Alo*Bhi ----
#pragma unroll
    for (int ks = 0; ks < 4; ++ks) {
        bf16x8 ah[2], al[2];
#pragma unroll
        for (int rb = 0; rb < 2; ++rb) {
            int arow = rb * 16 + cn;
            int aoff = (arow << 8) + swz(arow, (ks << 6) + (kg << 4));
            ah[rb] = *(const bf16x8*)((const char*)Ah + aoff);
            al[rb] = *(const bf16x8*)((const char*)Al + aoff);
        }
#pragma unroll
        for (int rb = 0; rb < 2; ++rb)
#pragma unroll
            for (int cb = 0; cb < 2; ++cb) {
                acc[rb][cb] = __builtin_amdgcn_mfma_f32_16x16x32_bf16(ah[rb], bh[cb][ks], acc[rb][cb], 0, 0, 0);
                acc[rb][cb] = __builtin_amdgcn_mfma_f32_16x16x32_bf16(ah[rb], bl[cb][ks], acc[rb][cb], 0, 0, 0);
                acc[rb][cb] = __builtin_amdgcn_mfma_f32_16x16x32_bf16(al[rb], bh[cb][ks], acc[rb][cb], 0, 0, 0);
            }
    }

    __syncthreads();   // all waves done reading Ah/Al

    // issue B2 loads early (hide L2 latency under epilogue VALU)
#pragma unroll
    for (int cb = 0; cb < 2; ++cb) {
        int n = cbase + cb * 16 + cn;
#pragma unroll
        for (int ks = 0; ks < 4; ++ks) {
            size_t o = (size_t)n * ND + ks * 32 + kg * 8;
            bh[cb][ks] = *(const bf16x8*)(w2h + o);
            bl[cb][ks] = *(const bf16x8*)(w2l + o);
        }
    }

    // ---- epilogue 1: H = relu(acc + b1) -> split bf16 -> LDS (reuse Ah/Al) ----
#pragma unroll
    for (int rb = 0; rb < 2; ++rb)
#pragma unroll
        for (int cb = 0; cb < 2; ++cb)
#pragma unroll
            for (int r = 0; r < 4; ++r) {
                float v = acc[rb][cb][r] + b1c[cb];
                v = fmaxf(v, 0.f);
                short h = f2bf(v);
                short l = f2bf(v - bf2f(h));
                int hrow  = rb * 16 + kg * 4 + r;
                int hcolb = (cbase + cb * 16 + cn) << 1;
                int hoff  = (hrow << 8) + swz(hrow, hcolb);
                *(short*)((char*)Ah + hoff) = h;
                *(short*)((char*)Al + hoff) = l;
                acc[rb][cb][r] = 0.f;
            }
    __syncthreads();   // H staged

    // ---- layer 2 ----
#pragma unroll
    for (int ks = 0; ks < 4; ++ks) {
        bf16x8 ah[2], al[2];
#pragma unroll
        for (int rb = 0; rb < 2; ++rb) {
            int arow = rb * 16 + cn;
            int aoff = (arow << 8) + swz(arow, (ks << 6) + (kg << 4));
            ah[rb] = *(const bf16x8*)((const char*)Ah + aoff);
            al[rb] = *(const bf16x8*)((const char*)Al + aoff);
        }
#pragma unroll
        for (int rb = 0; rb < 2; ++rb)
#pragma unroll
            for (int cb = 0; cb < 2; ++cb) {
                acc[rb][cb] = __builtin_amdgcn_mfma_f32_16x16x32_bf16(ah[rb], bh[cb][ks], acc[rb][cb], 0, 0, 0);
                acc[rb][cb] = __builtin_amdgcn_mfma_f32_16x16x32_bf16(ah[rb], bl[cb][ks], acc[rb][cb], 0, 0, 0);
                acc[rb][cb] = __builtin_amdgcn_mfma_f32_16x16x32_bf16(al[rb], bh[cb][ks], acc[rb][cb], 0, 0, 0);
            }
    }

    // ---- epilogue 2: store out' (no b2) + per-column BN partial stats ----
#pragma unroll
    for (int cb = 0; cb < 2; ++cb) {
        int col = cbase + cb * 16 + cn;
        float s = 0.f, s2 = 0.f;
#pragma unroll
        for (int rb = 0; rb < 2; ++rb)
#pragma unroll
            for (int r = 0; r < 4; ++r) {
                float v = acc[rb][cb][r];
                int row = row0 + rb * 16 + kg * 4 + r;
                if (row < M) {
                    out[(size_t)row * ND + col] = v;
                    s += v; s2 += v * v;
                }
            }
        // reduce over kg groups (lanes +32, +16), then one atomic per column
        s  += __shfl_down(s, 32, 64);
        s  += __shfl_down(s, 16, 64);
        s2 += __shfl_down(s2, 32, 64);
        s2 += __shfl_down(s2, 16, 64);
        if (kg == 0) {
            unsafeAtomicAdd(&ssum[col], s);
            unsafeAtomicAdd(&ssq[col], s2);
        }
    }
}

// ---------- K6: fold stats into (scale, shift) in place (b2 folded in) ----------
__global__ void bn_finalize_kernel(float* __restrict__ sum, float* __restrict__ sumsq,
                                   const float* __restrict__ g, const float* __restrict__ b,
                                   float M) {
    int c = threadIdx.x;
    float mean  = sum[c] / M;                       // mean of out' (b2 cancels in x-mean)
    float var   = sumsq[c] / M - mean * mean;
    float scale = g[c] * rsqrtf(var + BNEPS);
    sum[c]   = scale;                // scale
    sumsq[c] = b[c] - mean * scale;  // shift
}

// ---------- K7: BN apply in place ----------
__global__ __launch_bounds__(256) void bn_apply_kernel(
    float* __restrict__ x, int M,
    const float* __restrict__ scale, const float* __restrict__ shift) {
    size_t total4 = (size_t)M * (ND / 4);
    for (size_t i = (size_t)blockIdx.x * 256 + threadIdx.x; i < total4;
         i += (size_t)gridDim.x * 256) {
        int c = ((int)(i & 31)) << 2;
        float4 v = ((const float4*)x)[i];
        v.x = v.x * scale[c]     + shift[c];
        v.y = v.y * scale[c + 1] + shift[c + 1];
        v.z = v.z * scale[c + 2] + shift[c + 2];
        v.w = v.w * scale[c + 3] + shift[c + 3];
        ((float4*)x)[i] = v;
    }
}

extern "C" void kernel_launch(void* const* d_in, const int* in_sizes, int n_in,
                              void* d_out, int out_size, void* d_ws, size_t ws_size,
                              hipStream_t stream) {
    const float* nh       = (const float*)d_in[0];
    const float* eh       = (const float*)d_in[1];
    const int*   ei       = (const int*)d_in[2];
    const float* nf_eps   = (const float*)d_in[3];
    const float* ef_eps   = (const float*)d_in[4];
    const float* nf_W1    = (const float*)d_in[5];
    const float* nf_b1    = (const float*)d_in[6];
    const float* nf_W2    = (const float*)d_in[7];
    const float* nf_b2    = (const float*)d_in[8];
    const float* ef_W1    = (const float*)d_in[9];
    const float* ef_b1    = (const float*)d_in[10];
    const float* ef_W2    = (const float*)d_in[11];
    const float* ef_b2    = (const float*)d_in[12];
    const float* nf_gamma = (const float*)d_in[13];
    const float* nf_beta  = (const float*)d_in[14];
    const float* ef_gamma = (const float*)d_in[15];
    const float* ef_beta  = (const float*)d_in[16];

    float* out_n = (float*)d_out;                          // [N,128]
    float* out_e = (float*)d_out + (size_t)NNODES * ND;    // [E,128]

    char* ws = (char*)d_ws;
    size_t off = 0;
    auto alloc = [&](size_t bytes) -> void* {
        void* p = ws + off;
        off = (off + bytes + 255) & ~(size_t)255;
        return p;
    };
    float* attn   = (float*)alloc((size_t)NEDGES * 4);
    float* nz     = (float*)alloc((size_t)NNODES * ND * 4);
    int*   deg    = (int*)alloc((size_t)NNODES * 4);
    int*   slots  = (int*)alloc((size_t)NNODES * CAP * 4);
    float* ssum_n = (float*)alloc(ND * 4);
    float* ssq_n  = (float*)alloc(ND * 4);
    float* ssum_e = (float*)alloc(ND * 4);
    float* ssq_e  = (float*)alloc(ND * 4);
    short* nw1h   = (short*)alloc((size_t)ND * ND * 2);
    short* nw1l   = (short*)alloc((size_t)ND * ND * 2);
    short* nw2h   = (short*)alloc((size_t)ND * ND * 2);
    short* nw2l   = (short*)alloc((size_t)ND * ND * 2);
    short* ew1h   = (short*)alloc((size_t)ND * ND * 2);
    short* ew1l   = (short*)alloc((size_t)ND * ND * 2);
    short* ew2h   = (short*)alloc((size_t)ND * ND * 2);
    short* ew2l   = (short*)alloc((size_t)ND * ND * 2);

    hipMemsetAsync(deg,    0, (size_t)NNODES * 4, stream);
    hipMemsetAsync(ssum_n, 0, ND * 4, stream);
    hipMemsetAsync(ssq_n,  0, ND * 4, stream);
    hipMemsetAsync(ssum_e, 0, ND * 4, stream);
    hipMemsetAsync(ssq_e,  0, ND * 4, stream);

    prep_w_kernel<<<256, 128, 0, stream>>>(nf_W1, nf_W2, nw1h, nw1l, nw2h, nw2l);
    prep_w_kernel<<<256, 128, 0, stream>>>(ef_W1, ef_W2, ew1h, ew1l, ew2h, ew2l);

    attn_kernel<<<NEDGES / 8, 256, 0, stream>>>(nh, eh, ei, attn, deg, slots);
    gather_nz_kernel<<<(NNODES + 3) / 4, 256, 0, stream>>>(nh, ei, attn, deg, slots, nz);

    fused_mlp<0><<<(NNODES + BM - 1) / BM, 256, 0, stream>>>(
        nh, nw1h, nw1l, nf_b1, nw2h, nw2l, out_n, NNODES,
        nf_eps, nz, nullptr, ssum_n, ssq_n);
    fused_mlp<1><<<NEDGES / BM, 256, 0, stream>>>(
        eh, ew1h, ew1l, ef_b1, ew2h, ew2l, out_e, NEDGES,
        ef_eps, nz, ei, ssum_e, ssq_e);

    bn_finalize_kernel<<<1, 128, 0, stream>>>(ssum_n, ssq_n, nf_gamma, nf_beta, (float)NNODES);
    bn_finalize_kernel<<<1, 128, 0, stream>>>(ssum_e, ssq_e, ef_gamma, ef_beta, (float)NEDGES);
    bn_apply_kernel<<<2048, 256, 0, stream>>>(out_n, NNODES, ssum_n, ssq_n);
    bn_apply_kernel<<<8192, 256, 0, stream>>>(out_e, NEDGES, ssum_e, ssq_e);
}

// Round 6
// 1148.877 us; speedup vs baseline: 1.1843x; 1.1843x over previous
//
#include <hip/hip_runtime.h>
#include <cstdint>
#include <cstddef>

#define ND      128
#define NNODES  50000
#define NEDGES  640000
#define BNEPS   1e-5f
#define CAP     64   // max in-degree tracked; mean=12.8, P(deg>=64) ~ 1e-18
#define BM      64   // MLP row-tile (32KB LDS; B-table cost amortized per block)

typedef __attribute__((ext_vector_type(8))) short bf16x8;
typedef __attribute__((ext_vector_type(4))) short s16x4;
typedef __attribute__((ext_vector_type(4))) float f32x4;

__device__ __forceinline__ short f2bf(float x) {   // fp32 -> bf16 RNE
    unsigned u = __float_as_uint(x);
    unsigned r = u + 0x7fffu + ((u >> 16) & 1u);
    return (short)(r >> 16);
}
__device__ __forceinline__ float bf2f(short h) {
    return __uint_as_float(((unsigned)(unsigned short)h) << 16);
}
// XOR swizzle: spread 16B column-slots across banks per row (T2 / G4)
__device__ __forceinline__ int swz(int row, int colbyte) {
    return colbyte ^ ((row & 7) << 4);
}

// ---------- K0: split W (fp32 [k][n]) into transposed bf16 hi/lo [n][k] ----------
__global__ __launch_bounds__(128) void prep_w_kernel(
    const float* __restrict__ W1, const float* __restrict__ W2,
    short* __restrict__ w1h, short* __restrict__ w1l,
    short* __restrict__ w2h, short* __restrict__ w2l) {
    int k = blockIdx.x;            // 0..127 -> W1 row, 128..255 -> W2 row
    int n = threadIdx.x;           // 0..127 output column
    const float* W = (k < 128) ? W1 : W2;
    int kk = k & 127;
    float v = W[(size_t)kk * ND + n];
    short h = f2bf(v);
    short l = f2bf(v - bf2f(h));
    short* ph = (k < 128) ? w1h : w2h;
    short* pl = (k < 128) ? w1l : w2l;
    ph[(size_t)n * ND + kk] = h;
    pl[(size_t)n * ND + kk] = l;
}

// ---------- K1: per-edge attention logit + CSR fill (merged) ----------
__global__ __launch_bounds__(256) void attn_kernel(
    const float* __restrict__ nh, const float* __restrict__ eh,
    const int* __restrict__ ei, float* __restrict__ attn,
    int* __restrict__ deg, int* __restrict__ slots) {
    int gid = blockIdx.x * 256 + threadIdx.x;
    int e   = gid >> 5;
    int l   = threadIdx.x & 31;
    if (e >= NEDGES) return;
    int s = ei[e], d = ei[NEDGES + e];
    float4 sv = ((const float4*)(nh + (size_t)s * ND))[l];
    float4 dv = ((const float4*)(nh + (size_t)d * ND))[l];
    float4 ev = ((const float4*)(eh + (size_t)e * ND))[l];
    float acc = (sv.x + ev.x) * dv.x + (sv.y + ev.y) * dv.y +
                (sv.z + ev.z) * dv.z + (sv.w + ev.w) * dv.w;
#pragma unroll
    for (int off = 16; off > 0; off >>= 1) acc += __shfl_down(acc, off, 32);
    if (l == 0) {
        attn[e] = acc;
        int pos = atomicAdd(&deg[d], 1);
        if (pos < CAP) slots[(size_t)d * CAP + pos] = e;
    }
}

// ---------- K3: per-node softmax + weighted gather (one wave per node) ----------
__global__ __launch_bounds__(256) void gather_nz_kernel(
    const float* __restrict__ nh, const int* __restrict__ ei,
    const float* __restrict__ attn, const int* __restrict__ deg,
    const int* __restrict__ slots, float* __restrict__ nz) {
    int node = blockIdx.x * 4 + (threadIdx.x >> 6);
    int lane = threadIdx.x & 63;
    if (node >= NNODES) return;
    int dg = deg[node];
    if (dg > CAP) dg = CAP;

    int   e  = -1, si = 0;
    float a  = -3.0e38f;
    if (lane < dg) {
        e  = slots[(size_t)node * CAP + lane];
        a  = attn[e];
        si = ei[e];               // src node of this edge
    }
    float m = a;
#pragma unroll
    for (int off = 32; off > 0; off >>= 1) m = fmaxf(m, __shfl_xor(m, off, 64));
    float ex = (lane < dg) ? __expf(a - m) : 0.f;
    float sum = ex;
#pragma unroll
    for (int off = 32; off > 0; off >>= 1) sum += __shfl_xor(sum, off, 64);
    float rs = (dg > 0) ? 1.f / sum : 0.f;

    float2 acc = make_float2(0.f, 0.f);
    for (int i = 0; i < dg; ++i) {
        float al = __shfl(ex, i, 64) * rs;
        int   sv = __shfl(si, i, 64);
        float2 x = ((const float2*)(nh + (size_t)sv * ND))[lane];
        acc.x += al * x.x;
        acc.y += al * x.y;
    }
    ((float2*)(nz + (size_t)node * ND))[lane] = acc;
}

// ---------- K4: fused 2-layer MLP via split-fp32 bf16 MFMA + BN stats ----------
// MODE 0: X' = (1+eps)*nh + nz              (node, row-indexed nz)
// MODE 1: X' = (1+eps)*eh + nz[src]-nz[dst] (edge, gathered nz)
// out' = relu(X'@W1 + b1) @ W2   (b2 folded into BN shift: exact)
// 512 threads = 8 waves; wave w owns output cols [16w,16w+16).
// Per-ks JIT B loads (wrap-around prefetch, always initialized) keep
// VGPR <= 64 -> 8 waves/SIMD cap; LDS (32KB) then binds at 4 blocks/CU.
template <int MODE>
__global__ __launch_bounds__(512, 8) void fused_mlp(
    const float* __restrict__ X,
    const short* __restrict__ w1h, const short* __restrict__ w1l,
    const float* __restrict__ b1,
    const short* __restrict__ w2h, const short* __restrict__ w2l,
    float* __restrict__ out, int M,
    const float* __restrict__ eps, const float* __restrict__ nz,
    const int* __restrict__ ei,
    float* __restrict__ ssum, float* __restrict__ ssq) {
    __shared__ short Ah[BM * 128];
    __shared__ short Al[BM * 128];

    int tid  = threadIdx.x;
    int lane = tid & 63;
    int wv   = tid >> 6;    // 0..7
    int cn   = lane & 15;   // fragment col / A row within block
    int kg   = lane >> 4;   // k-group
    int row0 = blockIdx.x * BM;
    int ncol = wv * 16 + cn; // this lane's output column

    // ---- stage X' (BM x 128) as bf16 hi/lo into LDS (swizzled) ----
#pragma unroll
    for (int k = 0; k < BM / 16; ++k) {
        int i   = tid + k * 512;
        int r   = i >> 5;
        int c   = (i & 31) << 2;
        int row = row0 + r;
        float4 v = make_float4(0.f, 0.f, 0.f, 0.f);
        if (MODE == 1 || row < M) {
            float4 xv = *(const float4*)(X + (size_t)row * ND + c);
            float4 e4 = *(const float4*)(eps + c);
            if (MODE == 0) {
                float4 zv = *(const float4*)(nz + (size_t)row * ND + c);
                v.x = (1.f + e4.x) * xv.x + zv.x;
                v.y = (1.f + e4.y) * xv.y + zv.y;
                v.z = (1.f + e4.z) * xv.z + zv.z;
                v.w = (1.f + e4.w) * xv.w + zv.w;
            } else {
                int s = ei[row], d = ei[NEDGES + row];
                float4 zs = *(const float4*)(nz + (size_t)s * ND + c);
                float4 zd = *(const float4*)(nz + (size_t)d * ND + c);
                v.x = (1.f + e4.x) * xv.x + zs.x - zd.x;
                v.y = (1.f + e4.y) * xv.y + zs.y - zd.y;
                v.z = (1.f + e4.z) * xv.z + zs.z - zd.z;
                v.w = (1.f + e4.w) * xv.w + zs.w - zd.w;
            }
        }
        s16x4 hv, lv;
        hv.x = f2bf(v.x); lv.x = f2bf(v.x - bf2f(hv.x));
        hv.y = f2bf(v.y); lv.y = f2bf(v.y - bf2f(hv.y));
        hv.z = f2bf(v.z); lv.z = f2bf(v.z - bf2f(hv.z));
        hv.w = f2bf(v.w); lv.w = f2bf(v.w - bf2f(hv.w));
        int boff = (r << 8) + swz(r, c << 1);
        *(s16x4*)((char*)Ah + boff) = hv;
        *(s16x4*)((char*)Al + boff) = lv;
    }

    float b1c = b1[ncol];

    f32x4 acc[4];
#pragma unroll
    for (int rb = 0; rb < 4; ++rb) acc[rb] = (f32x4){0.f, 0.f, 0.f, 0.f};

    // prefetch first B1 fragments (overlaps barrier wait)
    bf16x8 bhc = *(const bf16x8*)(w1h + (size_t)ncol * ND + kg * 8);
    bf16x8 blc = *(const bf16x8*)(w1l + (size_t)ncol * ND + kg * 8);

    __syncthreads();   // A tile staged

    // ---- layer 1: acc += Ahi*Bhi + Ahi*Blo + Alo*Bhi (per-ks JIT B) ----
#pragma unroll
    for (int ks = 0; ks < 4; ++ks) {
        int ksn = (ks + 1) & 3;                      // wrap: ks=3 reloads ks0 (L1 hit)
        size_t o = (size_t)ncol * ND + ksn * 32 + kg * 8;
        bf16x8 bhn = *(const bf16x8*)(w1h + o);
        bf16x8 bln = *(const bf16x8*)(w1l + o);
        bf16x8 ah[4], al[4];
#pragma unroll
        for (int rb = 0; rb < 4; ++rb) {
            int arow = rb * 16 + cn;
            int aoff = (arow << 8) + swz(arow, (ks << 6) + (kg << 4));
            ah[rb] = *(const bf16x8*)((const char*)Ah + aoff);
            al[rb] = *(const bf16x8*)((const char*)Al + aoff);
        }
#pragma unroll
        for (int rb = 0; rb < 4; ++rb) {
            acc[rb] = __builtin_amdgcn_mfma_f32_16x16x32_bf16(ah[rb], bhc, acc[rb], 0, 0, 0);
            acc[rb] = __builtin_amdgcn_mfma_f32_16x16x32_bf16(ah[rb], blc, acc[rb], 0, 0, 0);
            acc[rb] = __builtin_amdgcn_mfma_f32_16x16x32_bf16(al[rb], bhc, acc[rb], 0, 0, 0);
        }
        bhc = bhn; blc = bln;
    }

    __syncthreads();   // all waves done reading Ah/Al

    // ---- epilogue 1: H = relu(acc + b1) -> split bf16 -> LDS (reuse Ah/Al) ----
#pragma unroll
    for (int rb = 0; rb < 4; ++rb)
#pragma unroll
        for (int r = 0; r < 4; ++r) {
            float v = acc[rb][r] + b1c;
            v = fmaxf(v, 0.f);
            short h = f2bf(v);
            short l = f2bf(v - bf2f(h));
            int hrow  = rb * 16 + kg * 4 + r;
            int hcolb = ncol << 1;
            int hoff  = (hrow << 8) + swz(hrow, hcolb);
            *(short*)((char*)Ah + hoff) = h;
            *(short*)((char*)Al + hoff) = l;
            acc[rb][r] = 0.f;
        }

    // prefetch first B2 fragments (overlaps barrier wait)
    bhc = *(const bf16x8*)(w2h + (size_t)ncol * ND + kg * 8);
    blc = *(const bf16x8*)(w2l + (size_t)ncol * ND + kg * 8);

    __syncthreads();   // H staged

    // ---- layer 2 ----
#pragma unroll
    for (int ks = 0; ks < 4; ++ks) {
        int ksn = (ks + 1) & 3;
        size_t o = (size_t)ncol * ND + ksn * 32 + kg * 8;
        bf16x8 bhn = *(const bf16x8*)(w2h + o);
        bf16x8 bln = *(const bf16x8*)(w2l + o);
        bf16x8 ah[4], al[4];
#pragma unroll
        for (int rb = 0; rb < 4; ++rb) {
            int arow = rb * 16 + cn;
            int aoff = (arow << 8) + swz(arow, (ks << 6) + (kg << 4));
            ah[rb] = *(const bf16x8*)((const char*)Ah + aoff);
            al[rb] = *(const bf16x8*)((const char*)Al + aoff);
        }
#pragma unroll
        for (int rb = 0; rb < 4; ++rb) {
            acc[rb] = __builtin_amdgcn_mfma_f32_16x16x32_bf16(ah[rb], bhc, acc[rb], 0, 0, 0);
            acc[rb] = __builtin_amdgcn_mfma_f32_16x16x32_bf16(ah[rb], blc, acc[rb], 0, 0, 0);
            acc[rb] = __builtin_amdgcn_mfma_f32_16x16x32_bf16(al[rb], bhc, acc[rb], 0, 0, 0);
        }
        bhc = bhn; blc = bln;
    }

    // ---- epilogue 2: store out' (no b2) + per-column BN partial stats ----
    {
        float s = 0.f, s2 = 0.f;
#pragma unroll
        for (int rb = 0; rb < 4; ++rb)
#pragma unroll
            for (int r = 0; r < 4; ++r) {
                float v = acc[rb][r];
                int row = row0 + rb * 16 + kg * 4 + r;
                if (row < M) {
                    out[(size_t)row * ND + ncol] = v;
                    s += v; s2 += v * v;
                }
            }
        // reduce over kg groups (lanes +32, +16), then one atomic per column
        s  += __shfl_down(s, 32, 64);
        s  += __shfl_down(s, 16, 64);
        s2 += __shfl_down(s2, 32, 64);
        s2 += __shfl_down(s2, 16, 64);
        if (kg == 0) {
            unsafeAtomicAdd(&ssum[ncol], s);
            unsafeAtomicAdd(&ssq[ncol], s2);
        }
    }
}

// ---------- K6: fold stats into (scale, shift) in place (b2 folded in) ----------
__global__ void bn_finalize_kernel(float* __restrict__ sum, float* __restrict__ sumsq,
                                   const float* __restrict__ g, const float* __restrict__ b,
                                   float M) {
    int c = threadIdx.x;
    float mean  = sum[c] / M;                       // mean of out' (b2 cancels in x-mean)
    float var   = sumsq[c] / M - mean * mean;
    float scale = g[c] * rsqrtf(var + BNEPS);
    sum[c]   = scale;                // scale
    sumsq[c] = b[c] - mean * scale;  // shift
}

// ---------- K7: BN apply in place ----------
__global__ __launch_bounds__(256) void bn_apply_kernel(
    float* __restrict__ x, int M,
    const float* __restrict__ scale, const float* __restrict__ shift) {
    size_t total4 = (size_t)M * (ND / 4);
    for (size_t i = (size_t)blockIdx.x * 256 + threadIdx.x; i < total4;
         i += (size_t)gridDim.x * 256) {
        int c = ((int)(i & 31)) << 2;
        float4 v = ((const float4*)x)[i];
        v.x = v.x * scale[c]     + shift[c];
        v.y = v.y * scale[c + 1] + shift[c + 1];
        v.z = v.z * scale[c + 2] + shift[c + 2];
        v.w = v.w * scale[c + 3] + shift[c + 3];
        ((float4*)x)[i] = v;
    }
}

extern "C" void kernel_launch(void* const* d_in, const int* in_sizes, int n_in,
                              void* d_out, int out_size, void* d_ws, size_t ws_size,
                              hipStream_t stream) {
    const float* nh       = (const float*)d_in[0];
    const float* eh       = (const float*)d_in[1];
    const int*   ei       = (const int*)d_in[2];
    const float* nf_eps   = (const float*)d_in[3];
    const float* ef_eps   = (const float*)d_in[4];
    const float* nf_W1    = (const float*)d_in[5];
    const float* nf_b1    = (const float*)d_in[6];
    const float* nf_W2    = (const float*)d_in[7];
    const float* nf_b2    = (const float*)d_in[8];
    const float* ef_W1    = (const float*)d_in[9];
    const float* ef_b1    = (const float*)d_in[10];
    const float* ef_W2    = (const float*)d_in[11];
    const float* ef_b2    = (const float*)d_in[12];
    const float* nf_gamma = (const float*)d_in[13];
    const float* nf_beta  = (const float*)d_in[14];
    const float* ef_gamma = (const float*)d_in[15];
    const float* ef_beta  = (const float*)d_in[16];

    float* out_n = (float*)d_out;                          // [N,128]
    float* out_e = (float*)d_out + (size_t)NNODES * ND;    // [E,128]

    char* ws = (char*)d_ws;
    size_t off = 0;
    auto alloc = [&](size_t bytes) -> void* {
        void* p = ws + off;
        off = (off + bytes + 255) & ~(size_t)255;
        return p;
    };
    float* attn   = (float*)alloc((size_t)NEDGES * 4);
    float* nz     = (float*)alloc((size_t)NNODES * ND * 4);
    int*   deg    = (int*)alloc((size_t)NNODES * 4);
    int*   slots  = (int*)alloc((size_t)NNODES * CAP * 4);
    float* ssum_n = (float*)alloc(ND * 4);
    float* ssq_n  = (float*)alloc(ND * 4);
    float* ssum_e = (float*)alloc(ND * 4);
    float* ssq_e  = (float*)alloc(ND * 4);
    short* nw1h   = (short*)alloc((size_t)ND * ND * 2);
    short* nw1l   = (short*)alloc((size_t)ND * ND * 2);
    short* nw2h   = (short*)alloc((size_t)ND * ND * 2);
    short* nw2l   = (short*)alloc((size_t)ND * ND * 2);
    short* ew1h   = (short*)alloc((size_t)ND * ND * 2);
    short* ew1l   = (short*)alloc((size_t)ND * ND * 2);
    short* ew2h   = (short*)alloc((size_t)ND * ND * 2);
    short* ew2l   = (short*)alloc((size_t)ND * ND * 2);

    hipMemsetAsync(deg,    0, (size_t)NNODES * 4, stream);
    hipMemsetAsync(ssum_n, 0, ND * 4, stream);
    hipMemsetAsync(ssq_n,  0, ND * 4, stream);
    hipMemsetAsync(ssum_e, 0, ND * 4, stream);
    hipMemsetAsync(ssq_e,  0, ND * 4, stream);

    prep_w_kernel<<<256, 128, 0, stream>>>(nf_W1, nf_W2, nw1h, nw1l, nw2h, nw2l);
    prep_w_kernel<<<256, 128, 0, stream>>>(ef_W1, ef_W2, ew1h, ew1l, ew2h, ew2l);

    attn_kernel<<<NEDGES / 8, 256, 0, stream>>>(nh, eh, ei, attn, deg, slots);
    gather_nz_kernel<<<(NNODES + 3) / 4, 256, 0, stream>>>(nh, ei, attn, deg, slots, nz);

    fused_mlp<0><<<(NNODES + BM - 1) / BM, 512, 0, stream>>>(
        nh, nw1h, nw1l, nf_b1, nw2h, nw2l, out_n, NNODES,
        nf_eps, nz, nullptr, ssum_n, ssq_n);
    fused_mlp<1><<<NEDGES / BM, 512, 0, stream>>>(
        eh, ew1h, ew1l, ef_b1, ew2h, ew2l, out_e, NEDGES,
        ef_eps, nz, ei, ssum_e, ssq_e);

    bn_finalize_kernel<<<1, 128, 0, stream>>>(ssum_n, ssq_n, nf_gamma, nf_beta, (float)NNODES);
    bn_finalize_kernel<<<1, 128, 0, stream>>>(ssum_e, ssq_e, ef_gamma, ef_beta, (float)NEDGES);
    bn_apply_kernel<<<2048, 256, 0, stream>>>(out_n, NNODES, ssum_n, ssq_n);
    bn_apply_kernel<<<8192, 256, 0, stream>>>(out_e, NEDGES, ssum_e, ssq_e);
}